// Round 3
// baseline (17340.091 us; speedup 1.0000x reference)
//
#include <hip/hip_runtime.h>
#include <hip/hip_bf16.h>
#include <stdint.h>

#define N_LEVELS   16
#define LOG2_T     19
#define TABLE_SIZE (1u << LOG2_T)
#define PRIME_Y    2654435761u
#define PRIME_Z    805459861u

typedef float v2f __attribute__((ext_vector_type(2)));

__device__ __forceinline__ void encode_point(float x0, float x1, float x2,
                                             const float* __restrict__ tables,
                                             const float* __restrict__ resolutions,
                                             float* __restrict__ a)
{
    #pragma unroll
    for (int l = 0; l < N_LEVELS; ++l) {
        const float res = resolutions[l];
        const float px = x0 * res, py = x1 * res, pz = x2 * res;
        const float fx = floorf(px), fy = floorf(py), fz = floorf(pz);
        const float wx = px - fx, wy = py - fy, wz = pz - fz;
        const uint32_t cx = (uint32_t)fx;
        const uint32_t cy = (uint32_t)fy;
        const uint32_t cz = (uint32_t)fz;

        const uint32_t hx0 = cx,           hx1 = cx + 1u;
        const uint32_t hy0 = cy * PRIME_Y, hy1 = hy0 + PRIME_Y;
        const uint32_t hz0 = cz * PRIME_Z, hz1 = hz0 + PRIME_Z;

        const float wx0 = 1.0f - wx, wy0 = 1.0f - wy, wz0 = 1.0f - wz;

        const float* __restrict__ tab = tables + (size_t)l * (size_t)TABLE_SIZE * 2u;

        float f0 = 0.0f, f1 = 0.0f;
        #pragma unroll
        for (int c = 0; c < 8; ++c) {
            const uint32_t h = ((c & 1) ? hx1 : hx0) ^
                               ((c & 2) ? hy1 : hy0) ^
                               ((c & 4) ? hz1 : hz0);
            const uint32_t idx = h & (TABLE_SIZE - 1u);
            const float2 fv = *(const float2*)(tab + 2u * idx);
            const float wgt = ((c & 1) ? wx : wx0) *
                              ((c & 2) ? wy : wy0) *
                              ((c & 4) ? wz : wz0);
            f0 = fmaf(wgt, fv.x, f0);
            f1 = fmaf(wgt, fv.y, f1);
        }
        a[2 * l + 0] = f0;
        a[2 * l + 1] = f1;
    }
}

// 2 points per thread; weights in LDS read once per point-PAIR (ds_read_b128
// amortized over both points); MLP packed over output-channel pairs as v2f
// -> v_pk_fma_f32 halves FMA instruction count. Weight v2f pairs are register
// subpairs of the float4 LDS read (zero repack).
__global__ __launch_bounds__(256, 2)
void hashgrid_mlp_kernel(const float* __restrict__ x,           // [N,3]
                         const float* __restrict__ tables,      // [16, T, 2]
                         const float* __restrict__ resolutions, // [16]
                         const float* __restrict__ W1,          // [32,64]
                         const float* __restrict__ b1,          // [64]
                         const float* __restrict__ W2,          // [64,64]
                         const float* __restrict__ b2,          // [64]
                         const float* __restrict__ W3,          // [64,1]
                         const float* __restrict__ b3,          // [1]
                         float* __restrict__ out,               // [N]
                         int n)
{
    __shared__ float sW1[32 * 64];
    __shared__ float sW2[64 * 64];
    __shared__ float sW3[64];
    __shared__ float sB1[64];
    __shared__ float sB2[64];
    __shared__ float sB3;

    {
        const int t = threadIdx.x;
        #pragma unroll
        for (int j = 0; j < 32 * 64; j += 256) sW1[j + t] = W1[j + t];
        #pragma unroll
        for (int j = 0; j < 64 * 64; j += 256) sW2[j + t] = W2[j + t];
        if (t < 64) {
            sW3[t] = W3[t];
            sB1[t] = b1[t];
            sB2[t] = b2[t];
        }
        if (t == 64) sB3 = b3[0];
    }
    __syncthreads();

    const int t  = blockIdx.x * blockDim.x + threadIdx.x;
    const int i0 = 2 * t;
    if (i0 >= n) return;
    const int i1 = (i0 + 1 < n) ? (i0 + 1) : i0;

    const float x0a = x[3 * i0 + 0] * 0.5f + 0.5f;
    const float x1a = x[3 * i0 + 1] * 0.5f + 0.5f;
    const float x2a = x[3 * i0 + 2] * 0.5f + 0.5f;
    const float x0b = x[3 * i1 + 0] * 0.5f + 0.5f;
    const float x1b = x[3 * i1 + 1] * 0.5f + 0.5f;
    const float x2b = x[3 * i1 + 2] * 0.5f + 0.5f;

    float aA[32], aB[32];
    encode_point(x0a, x1a, x2a, tables, resolutions, aA);
    encode_point(x0b, x1b, x2b, tables, resolutions, aB);

    const v2f zero = {0.0f, 0.0f};

    // ---- layer 1: [32] @ [32,64] + b1, relu ----
    v2f H1a[32], H1b[32];
    #pragma unroll
    for (int j2 = 0; j2 < 32; ++j2) {
        const v2f b = *(const v2f*)&sB1[2 * j2];
        H1a[j2] = b;
        H1b[j2] = b;
    }
    #pragma unroll
    for (int k = 0; k < 32; ++k) {
        const float akA = aA[k], akB = aB[k];
        const v2f vA = {akA, akA};
        const v2f vB = {akB, akB};
        #pragma unroll
        for (int j4 = 0; j4 < 16; ++j4) {
            const float4 w = *(const float4*)&sW1[k * 64 + j4 * 4];
            const v2f w01 = {w.x, w.y};
            const v2f w23 = {w.z, w.w};
            H1a[j4 * 2 + 0] = __builtin_elementwise_fma(vA, w01, H1a[j4 * 2 + 0]);
            H1a[j4 * 2 + 1] = __builtin_elementwise_fma(vA, w23, H1a[j4 * 2 + 1]);
            H1b[j4 * 2 + 0] = __builtin_elementwise_fma(vB, w01, H1b[j4 * 2 + 0]);
            H1b[j4 * 2 + 1] = __builtin_elementwise_fma(vB, w23, H1b[j4 * 2 + 1]);
        }
    }
    #pragma unroll
    for (int j2 = 0; j2 < 32; ++j2) {
        H1a[j2] = __builtin_elementwise_max(H1a[j2], zero);
        H1b[j2] = __builtin_elementwise_max(H1b[j2], zero);
    }

    // ---- layer 2 (two 32-wide halves) + layer 3 fused ----
    v2f accA = zero, accB = zero;
    #pragma unroll
    for (int half = 0; half < 2; ++half) {
        v2f H2a[16], H2b[16];
        #pragma unroll
        for (int j2 = 0; j2 < 16; ++j2) {
            const v2f b = *(const v2f*)&sB2[half * 32 + 2 * j2];
            H2a[j2] = b;
            H2b[j2] = b;
        }
        #pragma unroll
        for (int k2 = 0; k2 < 32; ++k2) {
            const v2f hA = H1a[k2];
            const v2f hB = H1b[k2];
            #pragma unroll
            for (int kk = 0; kk < 2; ++kk) {
                const float hkA = kk ? hA.y : hA.x;
                const float hkB = kk ? hB.y : hB.x;
                const v2f vA = {hkA, hkA};
                const v2f vB = {hkB, hkB};
                const int k = 2 * k2 + kk;
                #pragma unroll
                for (int j4 = 0; j4 < 8; ++j4) {
                    const float4 w = *(const float4*)&sW2[k * 64 + half * 32 + j4 * 4];
                    const v2f w01 = {w.x, w.y};
                    const v2f w23 = {w.z, w.w};
                    H2a[j4 * 2 + 0] = __builtin_elementwise_fma(vA, w01, H2a[j4 * 2 + 0]);
                    H2a[j4 * 2 + 1] = __builtin_elementwise_fma(vA, w23, H2a[j4 * 2 + 1]);
                    H2b[j4 * 2 + 0] = __builtin_elementwise_fma(vB, w01, H2b[j4 * 2 + 0]);
                    H2b[j4 * 2 + 1] = __builtin_elementwise_fma(vB, w23, H2b[j4 * 2 + 1]);
                }
            }
        }
        #pragma unroll
        for (int j2 = 0; j2 < 16; ++j2) {
            const v2f w3 = *(const v2f*)&sW3[half * 32 + 2 * j2];
            accA = __builtin_elementwise_fma(__builtin_elementwise_max(H2a[j2], zero), w3, accA);
            accB = __builtin_elementwise_fma(__builtin_elementwise_max(H2b[j2], zero), w3, accB);
        }
    }

    out[i0] = accA.x + accA.y + sB3;
    if (i0 + 1 < n) out[i0 + 1] = accB.x + accB.y + sB3;
}

extern "C" void kernel_launch(void* const* d_in, const int* in_sizes, int n_in,
                              void* d_out, int out_size, void* d_ws, size_t ws_size,
                              hipStream_t stream) {
    const float* x           = (const float*)d_in[0];
    const float* tables      = (const float*)d_in[1];
    const float* resolutions = (const float*)d_in[2];
    const float* W1          = (const float*)d_in[3];
    const float* b1          = (const float*)d_in[4];
    const float* W2          = (const float*)d_in[5];
    const float* b2          = (const float*)d_in[6];
    const float* W3          = (const float*)d_in[7];
    const float* b3          = (const float*)d_in[8];
    float* out               = (float*)d_out;

    const int n = out_size;  // 2,000,000
    const int block = 256;
    const int threads_needed = (n + 1) / 2;
    const int grid = (threads_needed + block - 1) / block;
    hashgrid_mlp_kernel<<<grid, block, 0, stream>>>(
        x, tables, resolutions, W1, b1, W2, b2, W3, b3, out, n);
}

// Round 4
// 1375.462 us; speedup vs baseline: 12.6067x; 12.6067x over previous
//
#include <hip/hip_runtime.h>
#include <hip/hip_bf16.h>
#include <stdint.h>

#define N_LEVELS   16
#define LOG2_T     19
#define TABLE_SIZE (1u << LOG2_T)
#define PRIME_Y    2654435761u
#define PRIME_Z    805459861u

// One thread per point. NO LDS: weights are wave-uniform -> scalar loads
// (s_load_dwordx16) + SGPR-operand v_fmac. Requirements for scalarization:
// fully-unrolled constant offsets, uniform control flow (no early return --
// index is clamped; duplicate writes to out[n-1] carry identical values),
// const __restrict__ inputs with only `out` written.
// Layer 1 is fused into the encode loop: each level's (f0,f1) is consumed
// immediately by 128 FMAs, interleaving VALU with gather latency and
// eliminating the a[32] array.
__global__ __launch_bounds__(256, 4)
void hashgrid_mlp_kernel(const float* __restrict__ x,           // [N,3]
                         const float* __restrict__ tables,      // [16, T, 2]
                         const float* __restrict__ resolutions, // [16]
                         const float* __restrict__ W1,          // [32,64]
                         const float* __restrict__ b1,          // [64]
                         const float* __restrict__ W2,          // [64,64]
                         const float* __restrict__ b2,          // [64]
                         const float* __restrict__ W3,          // [64,1]
                         const float* __restrict__ b3,          // [1]
                         float* __restrict__ out,               // [N]
                         int n)
{
    const int i  = blockIdx.x * blockDim.x + threadIdx.x;
    const int ip = (i < n) ? i : (n - 1);   // clamp: keeps CF uniform

    const float x0 = x[3 * ip + 0] * 0.5f + 0.5f;
    const float x1 = x[3 * ip + 1] * 0.5f + 0.5f;
    const float x2 = x[3 * ip + 2] * 0.5f + 0.5f;

    // ---- h1 accumulators seeded with bias; layer 1 fused into encode ----
    float h1[64];
    #pragma unroll
    for (int j = 0; j < 64; ++j) h1[j] = b1[j];

    #pragma unroll
    for (int l = 0; l < N_LEVELS; ++l) {
        const float res = resolutions[l];
        const float px = x0 * res, py = x1 * res, pz = x2 * res;
        const float fx = floorf(px), fy = floorf(py), fz = floorf(pz);
        const float wx = px - fx, wy = py - fy, wz = pz - fz;
        const uint32_t cx = (uint32_t)fx;
        const uint32_t cy = (uint32_t)fy;
        const uint32_t cz = (uint32_t)fz;

        const uint32_t hx0 = cx,           hx1 = cx + 1u;
        const uint32_t hy0 = cy * PRIME_Y, hy1 = hy0 + PRIME_Y;
        const uint32_t hz0 = cz * PRIME_Z, hz1 = hz0 + PRIME_Z;

        const float wx0 = 1.0f - wx, wy0 = 1.0f - wy, wz0 = 1.0f - wz;

        const float* __restrict__ tab = tables + (size_t)l * (size_t)TABLE_SIZE * 2u;

        float f0 = 0.0f, f1 = 0.0f;
        #pragma unroll
        for (int c = 0; c < 8; ++c) {
            const uint32_t h = ((c & 1) ? hx1 : hx0) ^
                               ((c & 2) ? hy1 : hy0) ^
                               ((c & 4) ? hz1 : hz0);
            const uint32_t idx = h & (TABLE_SIZE - 1u);
            const float2 fv = *(const float2*)(tab + 2u * idx);
            const float wgt = ((c & 1) ? wx : wx0) *
                              ((c & 2) ? wy : wy0) *
                              ((c & 4) ? wz : wz0);
            f0 = fmaf(wgt, fv.x, f0);
            f1 = fmaf(wgt, fv.y, f1);
        }

        // layer-1 contribution of this level's two features.
        // k-order preserved (2l before 2l+1) to keep reference summation order.
        const float* __restrict__ w1a = W1 + (2 * l + 0) * 64;
        const float* __restrict__ w1b = W1 + (2 * l + 1) * 64;
        #pragma unroll
        for (int j = 0; j < 64; ++j)
            h1[j] = fmaf(f1, w1b[j], fmaf(f0, w1a[j], h1[j]));
    }

    #pragma unroll
    for (int j = 0; j < 64; ++j) h1[j] = fmaxf(h1[j], 0.0f);

    // ---- layer 2 (two 32-wide halves) + layer 3 fused ----
    float accum = b3[0];
    #pragma unroll
    for (int half = 0; half < 2; ++half) {
        float h2[32];
        #pragma unroll
        for (int j = 0; j < 32; ++j) h2[j] = b2[half * 32 + j];
        #pragma unroll
        for (int k = 0; k < 64; ++k) {
            const float hk = h1[k];
            const float* __restrict__ w2row = W2 + k * 64 + half * 32;
            #pragma unroll
            for (int j = 0; j < 32; ++j)
                h2[j] = fmaf(hk, w2row[j], h2[j]);
        }
        #pragma unroll
        for (int j = 0; j < 32; ++j)
            accum = fmaf(fmaxf(h2[j], 0.0f), W3[half * 32 + j], accum);
    }

    out[ip] = accum;   // clamped lanes rewrite out[n-1] with the identical value
}

extern "C" void kernel_launch(void* const* d_in, const int* in_sizes, int n_in,
                              void* d_out, int out_size, void* d_ws, size_t ws_size,
                              hipStream_t stream) {
    const float* x           = (const float*)d_in[0];
    const float* tables      = (const float*)d_in[1];
    const float* resolutions = (const float*)d_in[2];
    const float* W1          = (const float*)d_in[3];
    const float* b1          = (const float*)d_in[4];
    const float* W2          = (const float*)d_in[5];
    const float* b2          = (const float*)d_in[6];
    const float* W3          = (const float*)d_in[7];
    const float* b3          = (const float*)d_in[8];
    float* out               = (float*)d_out;

    const int n = out_size;  // 2,000,000
    const int block = 256;
    const int grid = (n + block - 1) / block;
    hashgrid_mlp_kernel<<<grid, block, 0, stream>>>(
        x, tables, resolutions, W1, b1, W2, b2, W3, b3, out, n);
}